// Round 1
// 455.968 us; speedup vs baseline: 1.0781x; 1.0781x over previous
//
#include <hip/hip_runtime.h>
#include <hip/hip_bf16.h>
#include <math.h>

#define S_LEN 2048
#define NHEAD 16
#define DMODEL 1024

typedef short bf16x8 __attribute__((ext_vector_type(8)));
typedef float f32x4 __attribute__((ext_vector_type(4)));

static __device__ __forceinline__ unsigned short bfbits(float x) {
    __hip_bfloat16 h = __float2bfloat16(x);   // round-to-nearest
    unsigned short u; __builtin_memcpy(&u, &h, 2); return u;
}
static __device__ __forceinline__ float bf2f(unsigned short u) {
    union { unsigned int i; float f; } v; v.i = ((unsigned int)u) << 16; return v.f;
}
// round-to-nearest split: x ~= hi + lo, rel err ~2^-18
static __device__ __forceinline__ void splitRN(float x, unsigned short& hi, unsigned short& lo) {
    unsigned short h = bfbits(x);
    float r = x - bf2f(h);
    hi = h; lo = bfbits(r);
}

__device__ __forceinline__ int mask_at(const void* mp, int enc, int s) {
    if (enc) return ((const unsigned char*)mp)[s] != 0;
    return ((const unsigned int*)mp)[s] != 0u;
}

__global__ void detect_kernel(const void* __restrict__ mask, int* __restrict__ flags) {
    if (threadIdx.x == 0 && blockIdx.x == 0) {
        const unsigned int* m = (const unsigned int*)mask;
        int bytey = 0;
        for (int i = 0; i < 8; ++i) {
            unsigned int u = m[i];
            if (u != 0u && u != 1u && u != 0x3F800000u) bytey = 1;
        }
        flags[0] = bytey;
    }
}

// Pre-split X streams once (was redone 16x inside proj_fused, heavy VALU).
// out layout [s][k] row-major bf16. v: hi only.
__global__ __launch_bounds__(256)
void presplit_x(const float* __restrict__ Xq, const float* __restrict__ Xk,
                const float* __restrict__ Xv, const float* __restrict__ Xb,
                unsigned short* __restrict__ Xqh, unsigned short* __restrict__ Xql,
                unsigned short* __restrict__ Xkh, unsigned short* __restrict__ Xkl,
                unsigned short* __restrict__ Xvh,
                unsigned short* __restrict__ Xbh, unsigned short* __restrict__ Xbl) {
    size_t i4 = ((size_t)blockIdx.x * 256 + threadIdx.x) * 4;
    unsigned short h0,l0,h1,l1,h2,l2,h3,l3;
    float4 x = *(const float4*)&Xq[i4];
    splitRN(x.x,h0,l0); splitRN(x.y,h1,l1); splitRN(x.z,h2,l2); splitRN(x.w,h3,l3);
    *(ushort4*)&Xqh[i4] = make_ushort4(h0,h1,h2,h3);
    *(ushort4*)&Xql[i4] = make_ushort4(l0,l1,l2,l3);
    x = *(const float4*)&Xk[i4];
    splitRN(x.x,h0,l0); splitRN(x.y,h1,l1); splitRN(x.z,h2,l2); splitRN(x.w,h3,l3);
    *(ushort4*)&Xkh[i4] = make_ushort4(h0,h1,h2,h3);
    *(ushort4*)&Xkl[i4] = make_ushort4(l0,l1,l2,l3);
    x = *(const float4*)&Xv[i4];
    *(ushort4*)&Xvh[i4] = make_ushort4(bfbits(x.x),bfbits(x.y),bfbits(x.z),bfbits(x.w));
    x = *(const float4*)&Xb[i4];
    splitRN(x.x,h0,l0); splitRN(x.y,h1,l1); splitRN(x.z,h2,l2); splitRN(x.w,h3,l3);
    *(ushort4*)&Xbh[i4] = make_ushort4(h0,h1,h2,h3);
    *(ushort4*)&Xbl[i4] = make_ushort4(l0,l1,l2,l3);
}

// Pre-split + pre-transpose W once (was redone 32x per block with 8-way-conflict
// scalar LDS writes). in: ll [3][1024 d][16 h][64 n], bproj [1024][16][64].
// out: Wh/Wl [4 stream][16 h][64 n][1024 d] bf16. One block = (stream, h, 64-d tile).
__global__ __launch_bounds__(256)
void presplit_w(const float* __restrict__ ll, const float* __restrict__ bproj,
                unsigned short* __restrict__ Wh, unsigned short* __restrict__ Wl) {
    __shared__ unsigned short Th[64][72], Tl[64][72];   // [n][d_local]
    const int t = threadIdx.x;
    const int bid = blockIdx.x;
    const int stream = bid >> 8;
    const int rem = bid & 255;
    const int h = rem >> 4;
    const int d0 = (rem & 15) << 6;
    const float* src = (stream == 3) ? bproj : (ll + (size_t)stream * 1048576);
#pragma unroll
    for (int rep = 0; rep < 4; ++rep) {
        int fid = rep * 256 + t;
        int dl = fid >> 4, n4 = (fid & 15) * 4;
        float4 w = *(const float4*)&src[(size_t)(d0 + dl) * 1024 + h * 64 + n4];
        unsigned short hh, lo2;
#pragma unroll
        for (int m = 0; m < 4; ++m) { splitRN((&w.x)[m], hh, lo2); Th[n4+m][dl] = hh; Tl[n4+m][dl] = lo2; }
    }
    __syncthreads();
    size_t ob = (size_t)stream * 1048576 + (size_t)h * 65536 + d0;
#pragma unroll
    for (int rep = 0; rep < 2; ++rep) {
        int wid = rep * 256 + t;
        int n = wid >> 3, dl8 = (wid & 7) * 8;
        *(uint4*)&Wh[ob + (size_t)n * 1024 + dl8] = *(uint4*)&Th[n][dl8];
        *(uint4*)&Wl[ob + (size_t)n * 1024 + dl8] = *(uint4*)&Tl[n][dl8];
    }
}

// Fused q/k/v/b_rotate projection v2: inputs pre-split bf16.
// W fragments load global->register directly (per-wave private rows, L2-hit).
// X tiles reg-staged to LDS (vector writes, 2-way conflicts = free), one chunk ahead.
// LDS 35 KB (was 75 KB). One block = one (head, 64-row s-tile), 256 threads.
__global__ __launch_bounds__(256, 3)
void proj_fused2(const unsigned short* __restrict__ Xqh, const unsigned short* __restrict__ Xql,
                 const unsigned short* __restrict__ Xkh, const unsigned short* __restrict__ Xkl,
                 const unsigned short* __restrict__ Xvh,
                 const unsigned short* __restrict__ Xbh, const unsigned short* __restrict__ Xbl,
                 const unsigned short* __restrict__ Wh, const unsigned short* __restrict__ Wl,
                 unsigned short* __restrict__ qhi, unsigned short* __restrict__ qlo,
                 unsigned short* __restrict__ khi, unsigned short* __restrict__ klo,
                 unsigned short* __restrict__ vhi) {
    __shared__ unsigned short smem[7 * 2560];   // 7 arrays of [64][40]
    unsigned short (*XQh)[40] = (unsigned short(*)[40])(smem + 0 * 2560);
    unsigned short (*XQl)[40] = (unsigned short(*)[40])(smem + 1 * 2560);
    unsigned short (*XKh)[40] = (unsigned short(*)[40])(smem + 2 * 2560);
    unsigned short (*XKl)[40] = (unsigned short(*)[40])(smem + 3 * 2560);
    unsigned short (*XVh)[40] = (unsigned short(*)[40])(smem + 4 * 2560);
    unsigned short (*XBh)[40] = (unsigned short(*)[40])(smem + 5 * 2560);
    unsigned short (*XBl)[40] = (unsigned short(*)[40])(smem + 6 * 2560);
    unsigned short (*Vscr)[72] = (unsigned short(*)[72])smem;   // epilogue reuse

    const int t = threadIdx.x;
    const int h = blockIdx.x;
    const int s0 = blockIdx.y * 64;
    const int lane = t & 63, dt = t >> 6, quad = lane >> 4, c = lane & 15;

    f32x4 aq[4], ak[4], av[4], ab[4];
#pragma unroll
    for (int i = 0; i < 4; ++i) {
        aq[i] = (f32x4){0.f,0.f,0.f,0.f}; ak[i] = (f32x4){0.f,0.f,0.f,0.f};
        av[i] = (f32x4){0.f,0.f,0.f,0.f}; ab[i] = (f32x4){0.f,0.f,0.f,0.f};
    }

    // X stage addressing: one uint4 (8 bf16) per thread per array per chunk.
    const int xr = t >> 2, xk = (t & 3) * 8;
    const size_t xg = (size_t)(s0 + xr) * DMODEL + xk;
    // W fragment addressing: per-wave private rows [h][dt*16+c][k0 + quad*8 .. +8]
    const size_t wrow = (size_t)h * 65536 + (size_t)(dt * 16 + c) * 1024 + quad * 8;

    uint4 px[7];
    {   // prologue: chunk 0 X -> regs
        px[0] = *(const uint4*)&Xqh[xg]; px[1] = *(const uint4*)&Xql[xg];
        px[2] = *(const uint4*)&Xkh[xg]; px[3] = *(const uint4*)&Xkl[xg];
        px[4] = *(const uint4*)&Xvh[xg]; px[5] = *(const uint4*)&Xbh[xg];
        px[6] = *(const uint4*)&Xbl[xg];
    }

    for (int k0 = 0; k0 < DMODEL; k0 += 32) {
        __syncthreads();   // previous chunk's LDS readers done
        *(uint4*)&XQh[xr][xk] = px[0];
        *(uint4*)&XQl[xr][xk] = px[1];
        *(uint4*)&XKh[xr][xk] = px[2];
        *(uint4*)&XKl[xr][xk] = px[3];
        *(uint4*)&XVh[xr][xk] = px[4];
        *(uint4*)&XBh[xr][xk] = px[5];
        *(uint4*)&XBl[xr][xk] = px[6];
        __syncthreads();

        // W fragments for this chunk: issue first (MFMA waits on these only)
        bf16x8 aQh = *(const bf16x8*)&Wh[wrow + k0];
        bf16x8 aQl = *(const bf16x8*)&Wl[wrow + k0];
        bf16x8 aKh = *(const bf16x8*)&Wh[1048576 + wrow + k0];
        bf16x8 aKl = *(const bf16x8*)&Wl[1048576 + wrow + k0];
        bf16x8 aVh = *(const bf16x8*)&Wh[2097152 + wrow + k0];
        bf16x8 aVl = *(const bf16x8*)&Wl[2097152 + wrow + k0];
        bf16x8 aBh = *(const bf16x8*)&Wh[3145728 + wrow + k0];
        bf16x8 aBl = *(const bf16x8*)&Wl[3145728 + wrow + k0];

        // prefetch next chunk's X into regs (in flight across the MFMA loop)
        if (k0 + 32 < DMODEL) {
            size_t g = xg + k0 + 32;
            px[0] = *(const uint4*)&Xqh[g]; px[1] = *(const uint4*)&Xql[g];
            px[2] = *(const uint4*)&Xkh[g]; px[3] = *(const uint4*)&Xkl[g];
            px[4] = *(const uint4*)&Xvh[g]; px[5] = *(const uint4*)&Xbh[g];
            px[6] = *(const uint4*)&Xbl[g];
        }

#pragma unroll
        for (int st = 0; st < 4; ++st) {
            bf16x8 b1 = *(bf16x8*)&XQh[st*16+c][quad*8];
            bf16x8 b2 = *(bf16x8*)&XQl[st*16+c][quad*8];
            aq[st] = __builtin_amdgcn_mfma_f32_16x16x32_bf16(aQh, b1, aq[st], 0, 0, 0);
            aq[st] = __builtin_amdgcn_mfma_f32_16x16x32_bf16(aQh, b2, aq[st], 0, 0, 0);
            aq[st] = __builtin_amdgcn_mfma_f32_16x16x32_bf16(aQl, b1, aq[st], 0, 0, 0);
            aq[st] = __builtin_amdgcn_mfma_f32_16x16x32_bf16(aQl, b2, aq[st], 0, 0, 0);
            b1 = *(bf16x8*)&XKh[st*16+c][quad*8];
            b2 = *(bf16x8*)&XKl[st*16+c][quad*8];
            ak[st] = __builtin_amdgcn_mfma_f32_16x16x32_bf16(aKh, b1, ak[st], 0, 0, 0);
            ak[st] = __builtin_amdgcn_mfma_f32_16x16x32_bf16(aKh, b2, ak[st], 0, 0, 0);
            ak[st] = __builtin_amdgcn_mfma_f32_16x16x32_bf16(aKl, b1, ak[st], 0, 0, 0);
            ak[st] = __builtin_amdgcn_mfma_f32_16x16x32_bf16(aKl, b2, ak[st], 0, 0, 0);
            b1 = *(bf16x8*)&XVh[st*16+c][quad*8];
            av[st] = __builtin_amdgcn_mfma_f32_16x16x32_bf16(aVh, b1, av[st], 0, 0, 0);
            av[st] = __builtin_amdgcn_mfma_f32_16x16x32_bf16(aVl, b1, av[st], 0, 0, 0);
            b1 = *(bf16x8*)&XBh[st*16+c][quad*8];
            b2 = *(bf16x8*)&XBl[st*16+c][quad*8];
            ab[st] = __builtin_amdgcn_mfma_f32_16x16x32_bf16(aBh, b1, ab[st], 0, 0, 0);
            ab[st] = __builtin_amdgcn_mfma_f32_16x16x32_bf16(aBh, b2, ab[st], 0, 0, 0);
            ab[st] = __builtin_amdgcn_mfma_f32_16x16x32_bf16(aBl, b1, ab[st], 0, 0, 0);
            ab[st] = __builtin_amdgcn_mfma_f32_16x16x32_bf16(aBl, b2, ab[st], 0, 0, 0);
        }
    }

    // ---- q/k epilogue: RoPE * b, RN hi/lo stores (register-only) ----
    {
        int p0 = dt * 8 + 2 * quad;
        double inv0 = pow(10000.0, -(double)p0 / 32.0);
        double inv1 = pow(10000.0, -(double)(p0 + 1) / 32.0);
#pragma unroll
        for (int st = 0; st < 4; ++st) {
            int s = s0 + st * 16 + c;
            double a0 = (double)s * inv0, a1 = (double)s * inv1;
            float sn0 = (float)sin(a0), cs0 = (float)cos(a0);
            float sn1 = (float)sin(a1), cs1 = (float)cos(a1);
            size_t base = ((size_t)(h * S_LEN + s)) * 64 + dt * 16 + 4 * quad;
            unsigned short h0,l0,h1,l1,h2,l2,h3,l3;
            float r0 = (aq[st][0]*cs0 - aq[st][1]*sn0) * ab[st][0];
            float r1 = (aq[st][0]*sn0 + aq[st][1]*cs0) * ab[st][1];
            float r2 = (aq[st][2]*cs1 - aq[st][3]*sn1) * ab[st][2];
            float r3 = (aq[st][2]*sn1 + aq[st][3]*cs1) * ab[st][3];
            splitRN(r0,h0,l0); splitRN(r1,h1,l1); splitRN(r2,h2,l2); splitRN(r3,h3,l3);
            *(ushort4*)&qhi[base] = make_ushort4(h0,h1,h2,h3);
            *(ushort4*)&qlo[base] = make_ushort4(l0,l1,l2,l3);
            r0 = (ak[st][0]*cs0 - ak[st][1]*sn0) * ab[st][0];
            r1 = (ak[st][0]*sn0 + ak[st][1]*cs0) * ab[st][1];
            r2 = (ak[st][2]*cs1 - ak[st][3]*sn1) * ab[st][2];
            r3 = (ak[st][2]*sn1 + ak[st][3]*cs1) * ab[st][3];
            splitRN(r0,h0,l0); splitRN(r1,h1,l1); splitRN(r2,h2,l2); splitRN(r3,h3,l3);
            *(ushort4*)&khi[base] = make_ushort4(h0,h1,h2,h3);
            *(ushort4*)&klo[base] = make_ushort4(l0,l1,l2,l3);
        }
    }

    // ---- v epilogue: LDS transpose -> coalesced [h][d][s] uint4 stores ----
    __syncthreads();   // all MFMA LDS reads done; safe to reuse pool
#pragma unroll
    for (int st = 0; st < 4; ++st)
#pragma unroll
        for (int reg = 0; reg < 4; ++reg)
            Vscr[dt * 16 + 4 * quad + reg][st * 16 + c] = bfbits(av[st][reg]);
    __syncthreads();
#pragma unroll
    for (int i = 0; i < 2; ++i) {
        int id = i * 256 + t, d = id >> 3, s8 = (id & 7) * 8;
        size_t gb = ((size_t)(h * 64 + d)) * S_LEN + s0 + s8;
        *(uint4*)&vhi[gb] = *(uint4*)&Vscr[d][s8];
    }
}

// MFMA flash attention: QK 3-MFMA split-bf16, PV 2-MFMA (V hi-only); register softmax.
// out fp32 [s][h*64+d]. grid (32 q-tiles, 16 heads), 256 threads.
__global__ __launch_bounds__(256)
void attn_mfma(const unsigned short* __restrict__ qh, const unsigned short* __restrict__ ql,
               const unsigned short* __restrict__ kh, const unsigned short* __restrict__ kl,
               const unsigned short* __restrict__ vh,
               const void* __restrict__ mask, float* __restrict__ out,
               const int* __restrict__ flags) {
    __shared__ unsigned short Kh[64][72], Kl[64][72];   // [key][d]
    __shared__ unsigned short Vt[64][72];               // [d][key]
    __shared__ unsigned short Sh[64][72], Sl[64][72];   // P: [q-row][key]
    const int menc = flags[0];
    const int t = threadIdx.x;
    const int h = blockIdx.y;
    const int s0 = blockIdx.x * 64;
    const int lane = t & 63, w = t >> 6, quad = lane >> 4, c = lane & 15;

    bf16x8 qfh[2], qfl[2];
#pragma unroll
    for (int ks = 0; ks < 2; ++ks) {
        size_t base = ((size_t)(h * S_LEN + s0 + 16 * w + c)) * 64 + ks * 32 + quad * 8;
        qfh[ks] = *(const bf16x8*)&qh[base];
        qfl[ks] = *(const bf16x8*)&ql[base];
    }
    int mq[4];
#pragma unroll
    for (int i = 0; i < 4; ++i) mq[i] = mask_at(mask, menc, s0 + 16 * w + quad * 4 + i);

    float m_i[4], l_i[4];
#pragma unroll
    for (int i = 0; i < 4; ++i) { m_i[i] = -INFINITY; l_i[i] = 0.0f; }
    f32x4 o_acc[4];
#pragma unroll
    for (int i = 0; i < 4; ++i) o_acc[i] = (f32x4){0.f,0.f,0.f,0.f};

    uint4 pre[6];
#pragma unroll
    for (int i = 0; i < 2; ++i) {
        int id = i * 256 + t, row = id >> 3, col8 = (id & 7) * 8;
        size_t kb = ((size_t)(h * S_LEN + row)) * 64 + col8;
        size_t vb = ((size_t)(h * 64 + row)) * S_LEN + col8;
        pre[0 + i] = *(const uint4*)&kh[kb];
        pre[2 + i] = *(const uint4*)&kl[kb];
        pre[4 + i] = *(const uint4*)&vh[vb];
    }

    for (int kt = 0; kt < 32; ++kt) {
#pragma unroll
        for (int i = 0; i < 2; ++i) {
            int id = i * 256 + t, row = id >> 3, col8 = (id & 7) * 8;
            *(uint4*)&Kh[row][col8] = pre[0 + i];
            *(uint4*)&Kl[row][col8] = pre[2 + i];
            *(uint4*)&Vt[row][col8] = pre[4 + i];
        }
        int mk[4];
#pragma unroll
        for (int nt = 0; nt < 4; ++nt) mk[nt] = mask_at(mask, menc, kt * 64 + 16 * nt + c);
        __syncthreads();

        if (kt + 1 < 32) {
            const int kb0 = (kt + 1) * 64;
#pragma unroll
            for (int i = 0; i < 2; ++i) {
                int id = i * 256 + t, row = id >> 3, col8 = (id & 7) * 8;
                size_t kb = ((size_t)(h * S_LEN + kb0 + row)) * 64 + col8;
                size_t vb = ((size_t)(h * 64 + row)) * S_LEN + kb0 + col8;
                pre[0 + i] = *(const uint4*)&kh[kb];
                pre[2 + i] = *(const uint4*)&kl[kb];
                pre[4 + i] = *(const uint4*)&vh[vb];
            }
        }

        // ---- QK^T (3-MFMA split) ----
        f32x4 sc[4];
#pragma unroll
        for (int i = 0; i < 4; ++i) sc[i] = (f32x4){0.f,0.f,0.f,0.f};
#pragma unroll
        for (int nt = 0; nt < 4; ++nt)
#pragma unroll
            for (int ks = 0; ks < 2; ++ks) {
                bf16x8 kfh = *(bf16x8*)&Kh[nt * 16 + c][ks * 32 + quad * 8];
                bf16x8 kfl = *(bf16x8*)&Kl[nt * 16 + c][ks * 32 + quad * 8];
                sc[nt] = __builtin_amdgcn_mfma_f32_16x16x32_bf16(qfh[ks], kfh, sc[nt], 0, 0, 0);
                sc[nt] = __builtin_amdgcn_mfma_f32_16x16x32_bf16(qfh[ks], kfl, sc[nt], 0, 0, 0);
                sc[nt] = __builtin_amdgcn_mfma_f32_16x16x32_bf16(qfl[ks], kfh, sc[nt], 0, 0, 0);
            }

        float sm[4][4];
#pragma unroll
        for (int nt = 0; nt < 4; ++nt)
#pragma unroll
            for (int reg = 0; reg < 4; ++reg)
                sm[nt][reg] = (mq[reg] && mk[nt]) ? sc[nt][reg] * 0.125f : -1e30f;

        float rmax[4];
#pragma unroll
        for (int reg = 0; reg < 4; ++reg)
            rmax[reg] = fmaxf(fmaxf(sm[0][reg], sm[1][reg]), fmaxf(sm[2][reg], sm[3][reg]));
#pragma unroll
        for (int off = 1; off <= 8; off <<= 1)
#pragma unroll
            for (int reg = 0; reg < 4; ++reg)
                rmax[reg] = fmaxf(rmax[reg], __shfl_xor(rmax[reg], off, 64));

        float mn[4], alpha[4];
#pragma unroll
        for (int reg = 0; reg < 4; ++reg) {
            mn[reg] = fmaxf(m_i[reg], rmax[reg]);
            alpha[reg] = __expf(m_i[reg] - mn[reg]);
            m_i[reg] = mn[reg];
        }

        float rsum[4] = {0.f, 0.f, 0.f, 0.f};
#pragma unroll
        for (int nt = 0; nt < 4; ++nt)
#pragma unroll
            for (int reg = 0; reg < 4; ++reg) {
                float e = __expf(sm[nt][reg] - mn[reg]);
                rsum[reg] += e;
                unsigned short eh, el;
                splitRN(e, eh, el);
                Sh[16 * w + quad * 4 + reg][16 * nt + c] = eh;
                Sl[16 * w + quad * 4 + reg][16 * nt + c] = el;
            }
#pragma unroll
        for (int off = 1; off <= 8; off <<= 1)
#pragma unroll
            for (int reg = 0; reg < 4; ++reg)
                rsum[reg] += __shfl_xor(rsum[reg], off, 64);
#pragma unroll
        for (int reg = 0; reg < 4; ++reg) l_i[reg] = l_i[reg] * alpha[reg] + rsum[reg];
#pragma unroll
        for (int nt = 0; nt < 4; ++nt)
#pragma unroll
            for (int reg = 0; reg < 4; ++reg) o_acc[nt][reg] *= alpha[reg];

        __syncthreads();   // P visible

        // ---- PV (2-MFMA, V hi-only) ----
#pragma unroll
        for (int ks = 0; ks < 2; ++ks) {
            bf16x8 pfh = *(bf16x8*)&Sh[16 * w + c][ks * 32 + quad * 8];
            bf16x8 pfl = *(bf16x8*)&Sl[16 * w + c][ks * 32 + quad * 8];
#pragma unroll
            for (int nt = 0; nt < 4; ++nt) {
                bf16x8 vf = *(bf16x8*)&Vt[nt * 16 + c][ks * 32 + quad * 8];
                o_acc[nt] = __builtin_amdgcn_mfma_f32_16x16x32_bf16(pfh, vf, o_acc[nt], 0, 0, 0);
                o_acc[nt] = __builtin_amdgcn_mfma_f32_16x16x32_bf16(pfl, vf, o_acc[nt], 0, 0, 0);
            }
        }
        __syncthreads();   // safe to overwrite K/V/S
    }

#pragma unroll
    for (int reg = 0; reg < 4; ++reg) {
        float inv = 1.0f / l_i[reg];
        int row = s0 + 16 * w + quad * 4 + reg;
#pragma unroll
        for (int nt = 0; nt < 4; ++nt)
            out[(size_t)row * 1024 + h * 64 + nt * 16 + c] = o_acc[nt][reg] * inv;
    }
}

extern "C" void kernel_launch(void* const* d_in, const int* in_sizes, int n_in,
                              void* d_out, int out_size, void* d_ws, size_t ws_size,
                              hipStream_t stream) {
    const float* query = (const float*)d_in[0];
    const float* key   = (const float*)d_in[1];
    const float* value = (const float*)d_in[2];
    const float* b_emb = (const float*)d_in[3];
    const void*  mask  = d_in[4];
    const float* ll    = (const float*)d_in[5];
    const float* bproj = (const float*)d_in[6];
    float* out = (float*)d_out;

    const size_t HSD = (size_t)NHEAD * S_LEN * 64;     // 2M elements
    const size_t SD  = (size_t)S_LEN * DMODEL;         // 2M elements
    char* ws = (char*)d_ws;
    int* flags = (int*)ws;
    unsigned short* qhi = (unsigned short*)(ws + 4096);
    unsigned short* qlo = qhi + HSD;
    unsigned short* khi = qlo + HSD;
    unsigned short* klo = khi + HSD;
    unsigned short* vhi = klo + HSD;
    unsigned short* Xqh = vhi + HSD;
    unsigned short* Xql = Xqh + SD;
    unsigned short* Xkh = Xql + SD;
    unsigned short* Xkl = Xkh + SD;
    unsigned short* Xvh = Xkl + SD;
    unsigned short* Xbh = Xvh + SD;
    unsigned short* Xbl = Xbh + SD;
    unsigned short* Wh  = Xbl + SD;                    // 4M elements
    unsigned short* Wl  = Wh + 4 * 1048576;            // 4M elements
    // total: 4 KB + 20 MB + 28 MB + 16 MB = ~64 MB

    dim3 pb(256);
    detect_kernel<<<1, 64, 0, stream>>>(mask, flags);
    presplit_x<<<2048, pb, 0, stream>>>(query, key, value, b_emb,
                                        Xqh, Xql, Xkh, Xkl, Xvh, Xbh, Xbl);
    presplit_w<<<1024, pb, 0, stream>>>(ll, bproj, Wh, Wl);
    proj_fused2<<<dim3(16, 32), pb, 0, stream>>>(Xqh, Xql, Xkh, Xkl, Xvh, Xbh, Xbl,
                                                 Wh, Wl, qhi, qlo, khi, klo, vhi);
    attn_mfma<<<dim3(32, 16), pb, 0, stream>>>(qhi, qlo, khi, klo, vhi, mask, out, flags);
}

// Round 2
// 379.781 us; speedup vs baseline: 1.2944x; 1.2006x over previous
//
#include <hip/hip_runtime.h>
#include <hip/hip_bf16.h>
#include <math.h>

#define S_LEN 2048
#define NHEAD 16
#define DMODEL 1024

typedef short bf16x8 __attribute__((ext_vector_type(8)));
typedef float f32x4 __attribute__((ext_vector_type(4)));

static __device__ __forceinline__ unsigned short bfbits(float x) {
    __hip_bfloat16 h = __float2bfloat16(x);   // round-to-nearest
    unsigned short u; __builtin_memcpy(&u, &h, 2); return u;
}
static __device__ __forceinline__ float bf2f(unsigned short u) {
    union { unsigned int i; float f; } v; v.i = ((unsigned int)u) << 16; return v.f;
}
// round-to-nearest split: x ~= hi + lo, rel err ~2^-18
static __device__ __forceinline__ void splitRN(float x, unsigned short& hi, unsigned short& lo) {
    unsigned short h = bfbits(x);
    float r = x - bf2f(h);
    hi = h; lo = bfbits(r);
}

__device__ __forceinline__ int mask_at(const void* mp, int enc, int s) {
    if (enc) return ((const unsigned char*)mp)[s] != 0;
    return ((const unsigned int*)mp)[s] != 0u;
}

__global__ void detect_kernel(const void* __restrict__ mask, int* __restrict__ flags) {
    if (threadIdx.x == 0 && blockIdx.x == 0) {
        const unsigned int* m = (const unsigned int*)mask;
        int bytey = 0;
        for (int i = 0; i < 8; ++i) {
            unsigned int u = m[i];
            if (u != 0u && u != 1u && u != 0x3F800000u) bytey = 1;
        }
        flags[0] = bytey;
    }
}

// Pre-split X streams once. out layout [s][k] row-major bf16. v: hi only.
__global__ __launch_bounds__(256)
void presplit_x(const float* __restrict__ Xq, const float* __restrict__ Xk,
                const float* __restrict__ Xv, const float* __restrict__ Xb,
                unsigned short* __restrict__ Xqh, unsigned short* __restrict__ Xql,
                unsigned short* __restrict__ Xkh, unsigned short* __restrict__ Xkl,
                unsigned short* __restrict__ Xvh,
                unsigned short* __restrict__ Xbh, unsigned short* __restrict__ Xbl) {
    size_t i4 = ((size_t)blockIdx.x * 256 + threadIdx.x) * 4;
    unsigned short h0,l0,h1,l1,h2,l2,h3,l3;
    float4 x = *(const float4*)&Xq[i4];
    splitRN(x.x,h0,l0); splitRN(x.y,h1,l1); splitRN(x.z,h2,l2); splitRN(x.w,h3,l3);
    *(ushort4*)&Xqh[i4] = make_ushort4(h0,h1,h2,h3);
    *(ushort4*)&Xql[i4] = make_ushort4(l0,l1,l2,l3);
    x = *(const float4*)&Xk[i4];
    splitRN(x.x,h0,l0); splitRN(x.y,h1,l1); splitRN(x.z,h2,l2); splitRN(x.w,h3,l3);
    *(ushort4*)&Xkh[i4] = make_ushort4(h0,h1,h2,h3);
    *(ushort4*)&Xkl[i4] = make_ushort4(l0,l1,l2,l3);
    x = *(const float4*)&Xv[i4];
    *(ushort4*)&Xvh[i4] = make_ushort4(bfbits(x.x),bfbits(x.y),bfbits(x.z),bfbits(x.w));
    x = *(const float4*)&Xb[i4];
    splitRN(x.x,h0,l0); splitRN(x.y,h1,l1); splitRN(x.z,h2,l2); splitRN(x.w,h3,l3);
    *(ushort4*)&Xbh[i4] = make_ushort4(h0,h1,h2,h3);
    *(ushort4*)&Xbl[i4] = make_ushort4(l0,l1,l2,l3);
}

// Pre-split + pre-layout W in MFMA-fragment order:
// Wh/Wl[stream][h][dt][kc][lane][8] with lane = quad*16+c holding
// W[n = dt*16+c][d = kc*32 + quad*8 .. +8]. A wave's per-chunk fragment load
// is then ONE coalesced 1 KB read (was 16 scattered lines).
__global__ __launch_bounds__(256)
void presplit_w(const float* __restrict__ ll, const float* __restrict__ bproj,
                unsigned short* __restrict__ Wh, unsigned short* __restrict__ Wl) {
    __shared__ unsigned short Th[64][72], Tl[64][72];   // [n][d_local]
    const int t = threadIdx.x;
    const int bid = blockIdx.x;
    const int stream = bid >> 8;
    const int rem = bid & 255;
    const int h = rem >> 4;
    const int d0 = (rem & 15) << 6;
    const float* src = (stream == 3) ? bproj : (ll + (size_t)stream * 1048576);
#pragma unroll
    for (int rep = 0; rep < 4; ++rep) {
        int fid = rep * 256 + t;
        int dl = fid >> 4, n4 = (fid & 15) * 4;
        float4 w = *(const float4*)&src[(size_t)(d0 + dl) * 1024 + h * 64 + n4];
        unsigned short hh, lo2;
#pragma unroll
        for (int m = 0; m < 4; ++m) { splitRN((&w.x)[m], hh, lo2); Th[n4+m][dl] = hh; Tl[n4+m][dl] = lo2; }
    }
    __syncthreads();
    size_t obase = (size_t)stream * 1048576;
#pragma unroll
    for (int rep = 0; rep < 2; ++rep) {
        int wid = rep * 256 + t;
        int n = wid >> 3, dl8 = (wid & 7) * 8;
        int dtile = n >> 4, cc = n & 15;
        int dglob = d0 + dl8;
        int kc = dglob >> 5;
        int qd = (dglob >> 3) & 3;
        size_t off = obase + (size_t)(h * 4 + dtile) * 16384 + (size_t)kc * 512
                   + (size_t)(qd * 16 + cc) * 8;
        *(uint4*)&Wh[off] = *(uint4*)&Th[n][dl8];
        *(uint4*)&Wl[off] = *(uint4*)&Tl[n][dl8];
    }
}

// Fused q/k/v/b_rotate projection v3: W fragments coalesced + reg double-buffered;
// q/k epilogue via LDS transpose -> coalesced stores (kills RMW write amplification).
__global__ __launch_bounds__(256, 2)
void proj_fused3(const unsigned short* __restrict__ Xqh, const unsigned short* __restrict__ Xql,
                 const unsigned short* __restrict__ Xkh, const unsigned short* __restrict__ Xkl,
                 const unsigned short* __restrict__ Xvh,
                 const unsigned short* __restrict__ Xbh, const unsigned short* __restrict__ Xbl,
                 const unsigned short* __restrict__ Wh, const unsigned short* __restrict__ Wl,
                 unsigned short* __restrict__ qhi, unsigned short* __restrict__ qlo,
                 unsigned short* __restrict__ khi, unsigned short* __restrict__ klo,
                 unsigned short* __restrict__ vhi) {
    __shared__ unsigned short smem[23040];   // loop: 7x[64][40]; epilogue: 5x[64][72]
    unsigned short (*XQh)[40] = (unsigned short(*)[40])(smem + 0 * 2560);
    unsigned short (*XQl)[40] = (unsigned short(*)[40])(smem + 1 * 2560);
    unsigned short (*XKh)[40] = (unsigned short(*)[40])(smem + 2 * 2560);
    unsigned short (*XKl)[40] = (unsigned short(*)[40])(smem + 3 * 2560);
    unsigned short (*XVh)[40] = (unsigned short(*)[40])(smem + 4 * 2560);
    unsigned short (*XBh)[40] = (unsigned short(*)[40])(smem + 5 * 2560);
    unsigned short (*XBl)[40] = (unsigned short(*)[40])(smem + 6 * 2560);
    unsigned short (*Tqh)[72] = (unsigned short(*)[72])(smem + 0 * 4608);
    unsigned short (*Tql)[72] = (unsigned short(*)[72])(smem + 1 * 4608);
    unsigned short (*Tkh)[72] = (unsigned short(*)[72])(smem + 2 * 4608);
    unsigned short (*Tkl)[72] = (unsigned short(*)[72])(smem + 3 * 4608);
    unsigned short (*Tv)[72]  = (unsigned short(*)[72])(smem + 4 * 4608);

    const int t = threadIdx.x;
    const int h = blockIdx.x;
    const int s0 = blockIdx.y * 64;
    const int lane = t & 63, dt = t >> 6, quad = lane >> 4, c = lane & 15;

    f32x4 aq[4], ak[4], av[4], ab[4];
#pragma unroll
    for (int i = 0; i < 4; ++i) {
        aq[i] = (f32x4){0.f,0.f,0.f,0.f}; ak[i] = (f32x4){0.f,0.f,0.f,0.f};
        av[i] = (f32x4){0.f,0.f,0.f,0.f}; ab[i] = (f32x4){0.f,0.f,0.f,0.f};
    }

    const int xr = t >> 2, xk = (t & 3) * 8;
    const size_t xg = (size_t)(s0 + xr) * DMODEL + xk;
    const size_t wb = (size_t)(h * 4 + dt) * 16384 + (size_t)lane * 8;

    uint4 px[7];
    px[0] = *(const uint4*)&Xqh[xg]; px[1] = *(const uint4*)&Xql[xg];
    px[2] = *(const uint4*)&Xkh[xg]; px[3] = *(const uint4*)&Xkl[xg];
    px[4] = *(const uint4*)&Xvh[xg]; px[5] = *(const uint4*)&Xbh[xg];
    px[6] = *(const uint4*)&Xbl[xg];

    bf16x8 wQh = *(const bf16x8*)&Wh[wb];
    bf16x8 wQl = *(const bf16x8*)&Wl[wb];
    bf16x8 wKh = *(const bf16x8*)&Wh[1048576 + wb];
    bf16x8 wKl = *(const bf16x8*)&Wl[1048576 + wb];
    bf16x8 wVh = *(const bf16x8*)&Wh[2097152 + wb];
    bf16x8 wVl = *(const bf16x8*)&Wl[2097152 + wb];
    bf16x8 wBh = *(const bf16x8*)&Wh[3145728 + wb];
    bf16x8 wBl = *(const bf16x8*)&Wl[3145728 + wb];

#pragma unroll 2
    for (int kc = 0; kc < 32; ++kc) {
        __syncthreads();   // previous chunk's LDS readers done
        *(uint4*)&XQh[xr][xk] = px[0];
        *(uint4*)&XQl[xr][xk] = px[1];
        *(uint4*)&XKh[xr][xk] = px[2];
        *(uint4*)&XKl[xr][xk] = px[3];
        *(uint4*)&XVh[xr][xk] = px[4];
        *(uint4*)&XBh[xr][xk] = px[5];
        *(uint4*)&XBl[xr][xk] = px[6];
        __syncthreads();

        bf16x8 aQh = wQh, aQl = wQl, aKh = wKh, aKl = wKl;
        bf16x8 aVh = wVh, aVl = wVl, aBh = wBh, aBl = wBl;

        // prefetch next chunk's W fragments + X tile into regs (in flight across MFMAs)
        if (kc + 1 < 32) {
            size_t wo = wb + (size_t)(kc + 1) * 512;
            wQh = *(const bf16x8*)&Wh[wo];           wQl = *(const bf16x8*)&Wl[wo];
            wKh = *(const bf16x8*)&Wh[1048576 + wo]; wKl = *(const bf16x8*)&Wl[1048576 + wo];
            wVh = *(const bf16x8*)&Wh[2097152 + wo]; wVl = *(const bf16x8*)&Wl[2097152 + wo];
            wBh = *(const bf16x8*)&Wh[3145728 + wo]; wBl = *(const bf16x8*)&Wl[3145728 + wo];
            size_t g = xg + (size_t)(kc + 1) * 32;
            px[0] = *(const uint4*)&Xqh[g]; px[1] = *(const uint4*)&Xql[g];
            px[2] = *(const uint4*)&Xkh[g]; px[3] = *(const uint4*)&Xkl[g];
            px[4] = *(const uint4*)&Xvh[g]; px[5] = *(const uint4*)&Xbh[g];
            px[6] = *(const uint4*)&Xbl[g];
        }

#pragma unroll
        for (int st = 0; st < 4; ++st) {
            bf16x8 b1 = *(bf16x8*)&XQh[st*16+c][quad*8];
            bf16x8 b2 = *(bf16x8*)&XQl[st*16+c][quad*8];
            aq[st] = __builtin_amdgcn_mfma_f32_16x16x32_bf16(aQh, b1, aq[st], 0, 0, 0);
            aq[st] = __builtin_amdgcn_mfma_f32_16x16x32_bf16(aQh, b2, aq[st], 0, 0, 0);
            aq[st] = __builtin_amdgcn_mfma_f32_16x16x32_bf16(aQl, b1, aq[st], 0, 0, 0);
            aq[st] = __builtin_amdgcn_mfma_f32_16x16x32_bf16(aQl, b2, aq[st], 0, 0, 0);
            b1 = *(bf16x8*)&XKh[st*16+c][quad*8];
            b2 = *(bf16x8*)&XKl[st*16+c][quad*8];
            ak[st] = __builtin_amdgcn_mfma_f32_16x16x32_bf16(aKh, b1, ak[st], 0, 0, 0);
            ak[st] = __builtin_amdgcn_mfma_f32_16x16x32_bf16(aKh, b2, ak[st], 0, 0, 0);
            ak[st] = __builtin_amdgcn_mfma_f32_16x16x32_bf16(aKl, b1, ak[st], 0, 0, 0);
            ak[st] = __builtin_amdgcn_mfma_f32_16x16x32_bf16(aKl, b2, ak[st], 0, 0, 0);
            b1 = *(bf16x8*)&XVh[st*16+c][quad*8];
            av[st] = __builtin_amdgcn_mfma_f32_16x16x32_bf16(aVh, b1, av[st], 0, 0, 0);
            av[st] = __builtin_amdgcn_mfma_f32_16x16x32_bf16(aVl, b1, av[st], 0, 0, 0);
            b1 = *(bf16x8*)&XBh[st*16+c][quad*8];
            b2 = *(bf16x8*)&XBl[st*16+c][quad*8];
            ab[st] = __builtin_amdgcn_mfma_f32_16x16x32_bf16(aBh, b1, ab[st], 0, 0, 0);
            ab[st] = __builtin_amdgcn_mfma_f32_16x16x32_bf16(aBh, b2, ab[st], 0, 0, 0);
            ab[st] = __builtin_amdgcn_mfma_f32_16x16x32_bf16(aBl, b1, ab[st], 0, 0, 0);
            ab[st] = __builtin_amdgcn_mfma_f32_16x16x32_bf16(aBl, b2, ab[st], 0, 0, 0);
        }
    }

    // ---- epilogue: RoPE * b, then ALL outputs via LDS transpose -> coalesced stores ----
    __syncthreads();   // all MFMA LDS reads done; safe to reuse pool
    {
        int p0 = dt * 8 + 2 * quad;
        double inv0 = pow(10000.0, -(double)p0 / 32.0);
        double inv1 = pow(10000.0, -(double)(p0 + 1) / 32.0);
#pragma unroll
        for (int st = 0; st < 4; ++st) {
            int s = s0 + st * 16 + c;
            double a0 = (double)s * inv0, a1 = (double)s * inv1;
            float sn0 = (float)sin(a0), cs0 = (float)cos(a0);
            float sn1 = (float)sin(a1), cs1 = (float)cos(a1);
            unsigned short h0,l0,h1,l1,h2,l2,h3,l3;
            float r0 = (aq[st][0]*cs0 - aq[st][1]*sn0) * ab[st][0];
            float r1 = (aq[st][0]*sn0 + aq[st][1]*cs0) * ab[st][1];
            float r2 = (aq[st][2]*cs1 - aq[st][3]*sn1) * ab[st][2];
            float r3 = (aq[st][2]*sn1 + aq[st][3]*cs1) * ab[st][3];
            splitRN(r0,h0,l0); splitRN(r1,h1,l1); splitRN(r2,h2,l2); splitRN(r3,h3,l3);
            *(ushort4*)&Tqh[st*16+c][dt*16+4*quad] = make_ushort4(h0,h1,h2,h3);
            *(ushort4*)&Tql[st*16+c][dt*16+4*quad] = make_ushort4(l0,l1,l2,l3);
            r0 = (ak[st][0]*cs0 - ak[st][1]*sn0) * ab[st][0];
            r1 = (ak[st][0]*sn0 + ak[st][1]*cs0) * ab[st][1];
            r2 = (ak[st][2]*cs1 - ak[st][3]*sn1) * ab[st][2];
            r3 = (ak[st][2]*sn1 + ak[st][3]*cs1) * ab[st][3];
            splitRN(r0,h0,l0); splitRN(r1,h1,l1); splitRN(r2,h2,l2); splitRN(r3,h3,l3);
            *(ushort4*)&Tkh[st*16+c][dt*16+4*quad] = make_ushort4(h0,h1,h2,h3);
            *(ushort4*)&Tkl[st*16+c][dt*16+4*quad] = make_ushort4(l0,l1,l2,l3);
        }
    }
#pragma unroll
    for (int st = 0; st < 4; ++st)
#pragma unroll
        for (int reg = 0; reg < 4; ++reg)
            Tv[dt * 16 + 4 * quad + reg][st * 16 + c] = bfbits(av[st][reg]);
    __syncthreads();
#pragma unroll
    for (int i = 0; i < 2; ++i) {
        int id = i * 256 + t, row = id >> 3, d8 = (id & 7) * 8;
        size_t qb = ((size_t)(h * S_LEN + s0 + row)) * 64 + d8;
        *(uint4*)&qhi[qb] = *(uint4*)&Tqh[row][d8];
        *(uint4*)&qlo[qb] = *(uint4*)&Tql[row][d8];
        *(uint4*)&khi[qb] = *(uint4*)&Tkh[row][d8];
        *(uint4*)&klo[qb] = *(uint4*)&Tkl[row][d8];
        size_t vb = ((size_t)(h * 64 + row)) * S_LEN + s0 + d8;   // row = d, d8 = s-offset
        *(uint4*)&vhi[vb] = *(uint4*)&Tv[row][d8];
    }
}

// MFMA flash attention: double-buffered K/V LDS, 2 barriers/tile (was 3);
// staging ds_writes overlap QK+softmax. Math identical to prior round.
__global__ __launch_bounds__(256)
void attn_mfma(const unsigned short* __restrict__ qh, const unsigned short* __restrict__ ql,
               const unsigned short* __restrict__ kh, const unsigned short* __restrict__ kl,
               const unsigned short* __restrict__ vh,
               const void* __restrict__ mask, float* __restrict__ out,
               const int* __restrict__ flags) {
    __shared__ unsigned short Kh[2][64][72], Kl[2][64][72];   // [buf][key][d]
    __shared__ unsigned short Vt[2][64][72];                  // [buf][d][key]
    __shared__ unsigned short Sh[64][72], Sl[64][72];         // P: [q-row][key]
    const int menc = flags[0];
    const int t = threadIdx.x;
    const int h = blockIdx.y;
    const int s0 = blockIdx.x * 64;
    const int lane = t & 63, w = t >> 6, quad = lane >> 4, c = lane & 15;

    bf16x8 qfh[2], qfl[2];
#pragma unroll
    for (int ks = 0; ks < 2; ++ks) {
        size_t base = ((size_t)(h * S_LEN + s0 + 16 * w + c)) * 64 + ks * 32 + quad * 8;
        qfh[ks] = *(const bf16x8*)&qh[base];
        qfl[ks] = *(const bf16x8*)&ql[base];
    }
    int mq[4];
#pragma unroll
    for (int i = 0; i < 4; ++i) mq[i] = mask_at(mask, menc, s0 + 16 * w + quad * 4 + i);

    float m_i[4], l_i[4];
#pragma unroll
    for (int i = 0; i < 4; ++i) { m_i[i] = -INFINITY; l_i[i] = 0.0f; }
    f32x4 o_acc[4];
#pragma unroll
    for (int i = 0; i < 4; ++i) o_acc[i] = (f32x4){0.f,0.f,0.f,0.f};

    const int srow = t >> 3, scol8 = (t & 7) * 8;   // staging coords (id<512 half)
    uint4 pre[6];
#pragma unroll
    for (int i = 0; i < 2; ++i) {
        int id = i * 256 + t, row = id >> 3, col8 = (id & 7) * 8;
        size_t kb = ((size_t)(h * S_LEN + row)) * 64 + col8;
        size_t vb = ((size_t)(h * 64 + row)) * S_LEN + col8;
        pre[0 + i] = *(const uint4*)&kh[kb];
        pre[2 + i] = *(const uint4*)&kl[kb];
        pre[4 + i] = *(const uint4*)&vh[vb];
    }
#pragma unroll
    for (int i = 0; i < 2; ++i) {
        int id = i * 256 + t, row = id >> 3, col8 = (id & 7) * 8;
        *(uint4*)&Kh[0][row][col8] = pre[0 + i];
        *(uint4*)&Kl[0][row][col8] = pre[2 + i];
        *(uint4*)&Vt[0][row][col8] = pre[4 + i];
    }
    __syncthreads();

    int cur = 0;
    for (int kt = 0; kt < 32; ++kt) {
        // issue next-tile global loads first (hidden under QK + softmax)
        if (kt + 1 < 32) {
            const int kb0 = (kt + 1) * 64;
#pragma unroll
            for (int i = 0; i < 2; ++i) {
                int id = i * 256 + t, row = id >> 3, col8 = (id & 7) * 8;
                size_t kb = ((size_t)(h * S_LEN + kb0 + row)) * 64 + col8;
                size_t vb = ((size_t)(h * 64 + row)) * S_LEN + kb0 + col8;
                pre[0 + i] = *(const uint4*)&kh[kb];
                pre[2 + i] = *(const uint4*)&kl[kb];
                pre[4 + i] = *(const uint4*)&vh[vb];
            }
        }
        int mk[4];
#pragma unroll
        for (int nt = 0; nt < 4; ++nt) mk[nt] = mask_at(mask, menc, kt * 64 + 16 * nt + c);

        // ---- QK^T (3-MFMA split) ----
        f32x4 sc[4];
#pragma unroll
        for (int i = 0; i < 4; ++i) sc[i] = (f32x4){0.f,0.f,0.f,0.f};
#pragma unroll
        for (int nt = 0; nt < 4; ++nt)
#pragma unroll
            for (int ks = 0; ks < 2; ++ks) {
                bf16x8 kfh = *(bf16x8*)&Kh[cur][nt * 16 + c][ks * 32 + quad * 8];
                bf16x8 kfl = *(bf16x8*)&Kl[cur][nt * 16 + c][ks * 32 + quad * 8];
                sc[nt] = __builtin_amdgcn_mfma_f32_16x16x32_bf16(qfh[ks], kfh, sc[nt], 0, 0, 0);
                sc[nt] = __builtin_amdgcn_mfma_f32_16x16x32_bf16(qfh[ks], kfl, sc[nt], 0, 0, 0);
                sc[nt] = __builtin_amdgcn_mfma_f32_16x16x32_bf16(qfl[ks], kfh, sc[nt], 0, 0, 0);
            }

        float sm[4][4];
#pragma unroll
        for (int nt = 0; nt < 4; ++nt)
#pragma unroll
            for (int reg = 0; reg < 4; ++reg)
                sm[nt][reg] = (mq[reg] && mk[nt]) ? sc[nt][reg] * 0.125f : -1e30f;

        float rmax[4];
#pragma unroll
        for (int reg = 0; reg < 4; ++reg)
            rmax[reg] = fmaxf(fmaxf(sm[0][reg], sm[1][reg]), fmaxf(sm[2][reg], sm[3][reg]));
#pragma unroll
        for (int off = 1; off <= 8; off <<= 1)
#pragma unroll
            for (int reg = 0; reg < 4; ++reg)
                rmax[reg] = fmaxf(rmax[reg], __shfl_xor(rmax[reg], off, 64));

        float mn[4], alpha[4];
#pragma unroll
        for (int reg = 0; reg < 4; ++reg) {
            mn[reg] = fmaxf(m_i[reg], rmax[reg]);
            alpha[reg] = __expf(m_i[reg] - mn[reg]);
            m_i[reg] = mn[reg];
        }

        float rsum[4] = {0.f, 0.f, 0.f, 0.f};
#pragma unroll
        for (int nt = 0; nt < 4; ++nt)
#pragma unroll
            for (int reg = 0; reg < 4; ++reg) {
                float e = __expf(sm[nt][reg] - mn[reg]);
                rsum[reg] += e;
                unsigned short eh, el;
                splitRN(e, eh, el);
                Sh[16 * w + quad * 4 + reg][16 * nt + c] = eh;
                Sl[16 * w + quad * 4 + reg][16 * nt + c] = el;
            }
#pragma unroll
        for (int off = 1; off <= 8; off <<= 1)
#pragma unroll
            for (int reg = 0; reg < 4; ++reg)
                rsum[reg] += __shfl_xor(rsum[reg], off, 64);
#pragma unroll
        for (int reg = 0; reg < 4; ++reg) l_i[reg] = l_i[reg] * alpha[reg] + rsum[reg];
#pragma unroll
        for (int nt = 0; nt < 4; ++nt)
#pragma unroll
            for (int reg = 0; reg < 4; ++reg) o_acc[nt][reg] *= alpha[reg];

        // stage next tile into the other buffer (pre-loads have had QK+softmax to land)
        if (kt + 1 < 32) {
            const int nxt = cur ^ 1;
#pragma unroll
            for (int i = 0; i < 2; ++i) {
                int id = i * 256 + t, row = id >> 3, col8 = (id & 7) * 8;
                *(uint4*)&Kh[nxt][row][col8] = pre[0 + i];
                *(uint4*)&Kl[nxt][row][col8] = pre[2 + i];
                *(uint4*)&Vt[nxt][row][col8] = pre[4 + i];
            }
        }
        __syncthreads();   // P visible; next K/V visible for next iter

        // ---- PV (2-MFMA, V hi-only) ----
#pragma unroll
        for (int ks = 0; ks < 2; ++ks) {
            bf16x8 pfh = *(bf16x8*)&Sh[16 * w + c][ks * 32 + quad * 8];
            bf16x8 pfl = *(bf16x8*)&Sl[16 * w + c][ks * 32 + quad * 8];
#pragma unroll
            for (int nt = 0; nt < 4; ++nt) {
                bf16x8 vf = *(bf16x8*)&Vt[cur][nt * 16 + c][ks * 32 + quad * 8];
                o_acc[nt] = __builtin_amdgcn_mfma_f32_16x16x32_bf16(pfh, vf, o_acc[nt], 0, 0, 0);
                o_acc[nt] = __builtin_amdgcn_mfma_f32_16x16x32_bf16(pfl, vf, o_acc[nt], 0, 0, 0);
            }
        }
        __syncthreads();   // PV done: S reusable, old buffer free
        cur ^= 1;
    }

#pragma unroll
    for (int reg = 0; reg < 4; ++reg) {
        float inv = 1.0f / l_i[reg];
        int row = s0 + 16 * w + quad * 4 + reg;
#pragma unroll
        for (int nt = 0; nt < 4; ++nt)
            out[(size_t)row * 1024 + h * 64 + nt * 16 + c] = o_acc[nt][reg] * inv;
    }
}

extern "C" void kernel_launch(void* const* d_in, const int* in_sizes, int n_in,
                              void* d_out, int out_size, void* d_ws, size_t ws_size,
                              hipStream_t stream) {
    const float* query = (const float*)d_in[0];
    const float* key   = (const float*)d_in[1];
    const float* value = (const float*)d_in[2];
    const float* b_emb = (const float*)d_in[3];
    const void*  mask  = d_in[4];
    const float* ll    = (const float*)d_in[5];
    const float* bproj = (const float*)d_in[6];
    float* out = (float*)d_out;

    const size_t HSD = (size_t)NHEAD * S_LEN * 64;     // 2M elements
    const size_t SD  = (size_t)S_LEN * DMODEL;         // 2M elements
    char* ws = (char*)d_ws;
    int* flags = (int*)ws;
    unsigned short* qhi = (unsigned short*)(ws + 4096);
    unsigned short* qlo = qhi + HSD;
    unsigned short* khi = qlo + HSD;
    unsigned short* klo = khi + HSD;
    unsigned short* vhi = klo + HSD;
    unsigned short* Xqh = vhi + HSD;
    unsigned short* Xql = Xqh + SD;
    unsigned short* Xkh = Xql + SD;
    unsigned short* Xkl = Xkh + SD;
    unsigned short* Xvh = Xkl + SD;
    unsigned short* Xbh = Xvh + SD;
    unsigned short* Xbl = Xbh + SD;
    unsigned short* Wh  = Xbl + SD;                    // 4M elements
    unsigned short* Wl  = Wh + 4 * 1048576;            // 4M elements
    // total: 4 KB + 20 MB + 28 MB + 16 MB = ~64 MB

    dim3 pb(256);
    detect_kernel<<<1, 64, 0, stream>>>(mask, flags);
    presplit_x<<<2048, pb, 0, stream>>>(query, key, value, b_emb,
                                        Xqh, Xql, Xkh, Xkl, Xvh, Xbh, Xbl);
    presplit_w<<<1024, pb, 0, stream>>>(ll, bproj, Wh, Wl);
    proj_fused3<<<dim3(16, 32), pb, 0, stream>>>(Xqh, Xql, Xkh, Xkl, Xvh, Xbh, Xbl,
                                                 Wh, Wl, qhi, qlo, khi, klo, vhi);
    attn_mfma<<<dim3(32, 16), pb, 0, stream>>>(qhi, qlo, khi, klo, vhi, mask, out, flags);
}

// Round 3
// 263.238 us; speedup vs baseline: 1.8675x; 1.4427x over previous
//
#include <hip/hip_runtime.h>
#include <hip/hip_bf16.h>
#include <math.h>

#define S_LEN 2048
#define NHEAD 16
#define DMODEL 1024

typedef short bf16x8 __attribute__((ext_vector_type(8)));
typedef float f32x4 __attribute__((ext_vector_type(4)));

static __device__ __forceinline__ unsigned short bfbits(float x) {
    __hip_bfloat16 h = __float2bfloat16(x);   // round-to-nearest
    unsigned short u; __builtin_memcpy(&u, &h, 2); return u;
}
static __device__ __forceinline__ float bf2f(unsigned short u) {
    union { unsigned int i; float f; } v; v.i = ((unsigned int)u) << 16; return v.f;
}
// round-to-nearest split: x ~= hi + lo, rel err ~2^-18
static __device__ __forceinline__ void splitRN(float x, unsigned short& hi, unsigned short& lo) {
    unsigned short h = bfbits(x);
    float r = x - bf2f(h);
    hi = h; lo = bfbits(r);
}
static __device__ __forceinline__ void split4(float4 x, ushort4& h4, ushort4& l4) {
    unsigned short h0,l0,h1,l1,h2,l2,h3,l3;
    splitRN(x.x,h0,l0); splitRN(x.y,h1,l1); splitRN(x.z,h2,l2); splitRN(x.w,h3,l3);
    h4 = make_ushort4(h0,h1,h2,h3); l4 = make_ushort4(l0,l1,l2,l3);
}

__device__ __forceinline__ int mask_at(const void* mp, int enc, int s) {
    if (enc) return ((const unsigned char*)mp)[s] != 0;
    return ((const unsigned int*)mp)[s] != 0u;
}

__global__ void detect_kernel(const void* __restrict__ mask, int* __restrict__ flags) {
    if (threadIdx.x == 0 && blockIdx.x == 0) {
        const unsigned int* m = (const unsigned int*)mask;
        int bytey = 0;
        for (int i = 0; i < 8; ++i) {
            unsigned int u = m[i];
            if (u != 0u && u != 1u && u != 0x3F800000u) bytey = 1;
        }
        flags[0] = bytey;
    }
}

// Pre-split + pre-layout W in MFMA-fragment order:
// Wh/Wl[stream][h][dt][kc][lane][8] with lane = quad*16+c holding
// W[n = dt*16+c][d = kc*32 + quad*8 .. +8]. A wave's per-chunk fragment load
// is then ONE coalesced 1 KB read.
__global__ __launch_bounds__(256)
void presplit_w(const float* __restrict__ ll, const float* __restrict__ bproj,
                unsigned short* __restrict__ Wh, unsigned short* __restrict__ Wl) {
    __shared__ unsigned short Th[64][72], Tl[64][72];   // [n][d_local]
    const int t = threadIdx.x;
    const int bid = blockIdx.x;
    const int stream = bid >> 8;
    const int rem = bid & 255;
    const int h = rem >> 4;
    const int d0 = (rem & 15) << 6;
    const float* src = (stream == 3) ? bproj : (ll + (size_t)stream * 1048576);
#pragma unroll
    for (int rep = 0; rep < 4; ++rep) {
        int fid = rep * 256 + t;
        int dl = fid >> 4, n4 = (fid & 15) * 4;
        float4 w = *(const float4*)&src[(size_t)(d0 + dl) * 1024 + h * 64 + n4];
        unsigned short hh, lo2;
#pragma unroll
        for (int m = 0; m < 4; ++m) { splitRN((&w.x)[m], hh, lo2); Th[n4+m][dl] = hh; Tl[n4+m][dl] = lo2; }
    }
    __syncthreads();
    size_t obase = (size_t)stream * 1048576;
#pragma unroll
    for (int rep = 0; rep < 2; ++rep) {
        int wid = rep * 256 + t;
        int n = wid >> 3, dl8 = (wid & 7) * 8;
        int dtile = n >> 4, cc = n & 15;
        int dglob = d0 + dl8;
        int kc = dglob >> 5;
        int qd = (dglob >> 3) & 3;
        size_t off = obase + (size_t)(h * 4 + dtile) * 16384 + (size_t)kc * 512
                   + (size_t)(qd * 16 + cc) * 8;
        *(uint4*)&Wh[off] = *(uint4*)&Th[n][dl8];
        *(uint4*)&Wl[off] = *(uint4*)&Tl[n][dl8];
    }
}

// Fused q/k/v/b_rotate projection v4: reads RAW f32 X (split fused in-loop, no
// intermediate round-trip), W fragments coalesced + reg double-buffered.
// XCD-exclusive s-tile swizzle: XCD k owns s-tiles 4k..4k+3 -> X L2-resident,
// fetched once per XCD (was 8x cross-XCD re-fetch = 224 MB).
// LDS 35840 B (2-pass epilogue transpose).
__global__ __launch_bounds__(256, 2)
void proj_fused4(const float* __restrict__ Xq, const float* __restrict__ Xk,
                 const float* __restrict__ Xv, const float* __restrict__ Xb,
                 const unsigned short* __restrict__ Wh, const unsigned short* __restrict__ Wl,
                 unsigned short* __restrict__ qhi, unsigned short* __restrict__ qlo,
                 unsigned short* __restrict__ khi, unsigned short* __restrict__ klo,
                 unsigned short* __restrict__ vhi) {
    __shared__ unsigned short smem[17920];   // loop: 7x[64][40]; epilogue: 3x[64][72]
    unsigned short (*XQh)[40] = (unsigned short(*)[40])(smem + 0 * 2560);
    unsigned short (*XQl)[40] = (unsigned short(*)[40])(smem + 1 * 2560);
    unsigned short (*XKh)[40] = (unsigned short(*)[40])(smem + 2 * 2560);
    unsigned short (*XKl)[40] = (unsigned short(*)[40])(smem + 3 * 2560);
    unsigned short (*XVh)[40] = (unsigned short(*)[40])(smem + 4 * 2560);
    unsigned short (*XBh)[40] = (unsigned short(*)[40])(smem + 5 * 2560);
    unsigned short (*XBl)[40] = (unsigned short(*)[40])(smem + 6 * 2560);
    unsigned short (*T0)[72] = (unsigned short(*)[72])(smem + 0 * 4608);
    unsigned short (*T1)[72] = (unsigned short(*)[72])(smem + 1 * 4608);
    unsigned short (*T2)[72] = (unsigned short(*)[72])(smem + 2 * 4608);

    const int t = threadIdx.x;
    // XCD-exclusive s-tile swizzle (bijective: 512 = 8 xcd * 16 h * 4 sg)
    const int lin = blockIdx.x + (blockIdx.y << 4);
    const int xcd = lin & 7;
    const int h = (lin >> 3) & 15;
    const int s0 = (xcd * 4 + (lin >> 7)) * 64;
    const int lane = t & 63, dt = t >> 6, quad = lane >> 4, c = lane & 15;

    f32x4 aq[4], ak[4], av[4], ab[4];
#pragma unroll
    for (int i = 0; i < 4; ++i) {
        aq[i] = (f32x4){0.f,0.f,0.f,0.f}; ak[i] = (f32x4){0.f,0.f,0.f,0.f};
        av[i] = (f32x4){0.f,0.f,0.f,0.f}; ab[i] = (f32x4){0.f,0.f,0.f,0.f};
    }

    // X stage addressing: 8 floats (2 float4) per thread per stream per chunk.
    const int xr = t >> 2, xk = (t & 3) * 8;
    const size_t xg = (size_t)(s0 + xr) * DMODEL + xk;
    // W fragment addressing: per-wave coalesced 1 KB fragment rows
    const size_t wb = (size_t)(h * 4 + dt) * 16384 + (size_t)lane * 8;

    float4 pq[2], pk[2], pv[2], pb[2];
    pq[0] = *(const float4*)&Xq[xg]; pq[1] = *(const float4*)&Xq[xg + 4];
    pk[0] = *(const float4*)&Xk[xg]; pk[1] = *(const float4*)&Xk[xg + 4];
    pv[0] = *(const float4*)&Xv[xg]; pv[1] = *(const float4*)&Xv[xg + 4];
    pb[0] = *(const float4*)&Xb[xg]; pb[1] = *(const float4*)&Xb[xg + 4];

    bf16x8 wQh = *(const bf16x8*)&Wh[wb];
    bf16x8 wQl = *(const bf16x8*)&Wl[wb];
    bf16x8 wKh = *(const bf16x8*)&Wh[1048576 + wb];
    bf16x8 wKl = *(const bf16x8*)&Wl[1048576 + wb];
    bf16x8 wVh = *(const bf16x8*)&Wh[2097152 + wb];
    bf16x8 wVl = *(const bf16x8*)&Wl[2097152 + wb];
    bf16x8 wBh = *(const bf16x8*)&Wh[3145728 + wb];
    bf16x8 wBl = *(const bf16x8*)&Wl[3145728 + wb];

    for (int kc = 0; kc < 32; ++kc) {
        __syncthreads();   // previous chunk's LDS readers done
        {
            ushort4 h4, l4;
            split4(pq[0], h4, l4); *(ushort4*)&XQh[xr][xk]   = h4; *(ushort4*)&XQl[xr][xk]   = l4;
            split4(pq[1], h4, l4); *(ushort4*)&XQh[xr][xk+4] = h4; *(ushort4*)&XQl[xr][xk+4] = l4;
            split4(pk[0], h4, l4); *(ushort4*)&XKh[xr][xk]   = h4; *(ushort4*)&XKl[xr][xk]   = l4;
            split4(pk[1], h4, l4); *(ushort4*)&XKh[xr][xk+4] = h4; *(ushort4*)&XKl[xr][xk+4] = l4;
            split4(pb[0], h4, l4); *(ushort4*)&XBh[xr][xk]   = h4; *(ushort4*)&XBl[xr][xk]   = l4;
            split4(pb[1], h4, l4); *(ushort4*)&XBh[xr][xk+4] = h4; *(ushort4*)&XBl[xr][xk+4] = l4;
            *(ushort4*)&XVh[xr][xk]   = make_ushort4(bfbits(pv[0].x),bfbits(pv[0].y),bfbits(pv[0].z),bfbits(pv[0].w));
            *(ushort4*)&XVh[xr][xk+4] = make_ushort4(bfbits(pv[1].x),bfbits(pv[1].y),bfbits(pv[1].z),bfbits(pv[1].w));
        }
        __syncthreads();

        bf16x8 aQh = wQh, aQl = wQl, aKh = wKh, aKl = wKl;
        bf16x8 aVh = wVh, aVl = wVl, aBh = wBh, aBl = wBl;

        // prefetch next chunk's W fragments + raw X into regs (in flight across MFMAs)
        if (kc + 1 < 32) {
            size_t wo = wb + (size_t)(kc + 1) * 512;
            wQh = *(const bf16x8*)&Wh[wo];           wQl = *(const bf16x8*)&Wl[wo];
            wKh = *(const bf16x8*)&Wh[1048576 + wo]; wKl = *(const bf16x8*)&Wl[1048576 + wo];
            wVh = *(const bf16x8*)&Wh[2097152 + wo]; wVl = *(const bf16x8*)&Wl[2097152 + wo];
            wBh = *(const bf16x8*)&Wh[3145728 + wo]; wBl = *(const bf16x8*)&Wl[3145728 + wo];
            size_t g = xg + (size_t)(kc + 1) * 32;
            pq[0] = *(const float4*)&Xq[g]; pq[1] = *(const float4*)&Xq[g + 4];
            pk[0] = *(const float4*)&Xk[g]; pk[1] = *(const float4*)&Xk[g + 4];
            pv[0] = *(const float4*)&Xv[g]; pv[1] = *(const float4*)&Xv[g + 4];
            pb[0] = *(const float4*)&Xb[g]; pb[1] = *(const float4*)&Xb[g + 4];
        }

#pragma unroll
        for (int st = 0; st < 4; ++st) {
            bf16x8 b1 = *(bf16x8*)&XQh[st*16+c][quad*8];
            bf16x8 b2 = *(bf16x8*)&XQl[st*16+c][quad*8];
            aq[st] = __builtin_amdgcn_mfma_f32_16x16x32_bf16(aQh, b1, aq[st], 0, 0, 0);
            aq[st] = __builtin_amdgcn_mfma_f32_16x16x32_bf16(aQh, b2, aq[st], 0, 0, 0);
            aq[st] = __builtin_amdgcn_mfma_f32_16x16x32_bf16(aQl, b1, aq[st], 0, 0, 0);
            aq[st] = __builtin_amdgcn_mfma_f32_16x16x32_bf16(aQl, b2, aq[st], 0, 0, 0);
            b1 = *(bf16x8*)&XKh[st*16+c][quad*8];
            b2 = *(bf16x8*)&XKl[st*16+c][quad*8];
            ak[st] = __builtin_amdgcn_mfma_f32_16x16x32_bf16(aKh, b1, ak[st], 0, 0, 0);
            ak[st] = __builtin_amdgcn_mfma_f32_16x16x32_bf16(aKh, b2, ak[st], 0, 0, 0);
            ak[st] = __builtin_amdgcn_mfma_f32_16x16x32_bf16(aKl, b1, ak[st], 0, 0, 0);
            ak[st] = __builtin_amdgcn_mfma_f32_16x16x32_bf16(aKl, b2, ak[st], 0, 0, 0);
            b1 = *(bf16x8*)&XVh[st*16+c][quad*8];
            av[st] = __builtin_amdgcn_mfma_f32_16x16x32_bf16(aVh, b1, av[st], 0, 0, 0);
            av[st] = __builtin_amdgcn_mfma_f32_16x16x32_bf16(aVl, b1, av[st], 0, 0, 0);
            b1 = *(bf16x8*)&XBh[st*16+c][quad*8];
            b2 = *(bf16x8*)&XBl[st*16+c][quad*8];
            ab[st] = __builtin_amdgcn_mfma_f32_16x16x32_bf16(aBh, b1, ab[st], 0, 0, 0);
            ab[st] = __builtin_amdgcn_mfma_f32_16x16x32_bf16(aBh, b2, ab[st], 0, 0, 0);
            ab[st] = __builtin_amdgcn_mfma_f32_16x16x32_bf16(aBl, b1, ab[st], 0, 0, 0);
            ab[st] = __builtin_amdgcn_mfma_f32_16x16x32_bf16(aBl, b2, ab[st], 0, 0, 0);
        }
    }

    // ---- epilogue: RoPE * b in regs, then 2-pass LDS transpose -> coalesced stores ----
    float rq[4][4], rk[4][4];
    {
        int p0 = dt * 8 + 2 * quad;
        double inv0 = pow(10000.0, -(double)p0 / 32.0);
        double inv1 = pow(10000.0, -(double)(p0 + 1) / 32.0);
#pragma unroll
        for (int st = 0; st < 4; ++st) {
            int s = s0 + st * 16 + c;
            double a0 = (double)s * inv0, a1 = (double)s * inv1;
            float sn0 = (float)sin(a0), cs0 = (float)cos(a0);
            float sn1 = (float)sin(a1), cs1 = (float)cos(a1);
            rq[st][0] = (aq[st][0]*cs0 - aq[st][1]*sn0) * ab[st][0];
            rq[st][1] = (aq[st][0]*sn0 + aq[st][1]*cs0) * ab[st][1];
            rq[st][2] = (aq[st][2]*cs1 - aq[st][3]*sn1) * ab[st][2];
            rq[st][3] = (aq[st][2]*sn1 + aq[st][3]*cs1) * ab[st][3];
            rk[st][0] = (ak[st][0]*cs0 - ak[st][1]*sn0) * ab[st][0];
            rk[st][1] = (ak[st][0]*sn0 + ak[st][1]*cs0) * ab[st][1];
            rk[st][2] = (ak[st][2]*cs1 - ak[st][3]*sn1) * ab[st][2];
            rk[st][3] = (ak[st][2]*sn1 + ak[st][3]*cs1) * ab[st][3];
        }
    }
    // pass A: q hi/lo + v
    __syncthreads();   // all MFMA LDS reads done; safe to reuse pool
#pragma unroll
    for (int st = 0; st < 4; ++st) {
        unsigned short h0,l0,h1,l1,h2,l2,h3,l3;
        splitRN(rq[st][0],h0,l0); splitRN(rq[st][1],h1,l1);
        splitRN(rq[st][2],h2,l2); splitRN(rq[st][3],h3,l3);
        *(ushort4*)&T0[st*16+c][dt*16+4*quad] = make_ushort4(h0,h1,h2,h3);
        *(ushort4*)&T1[st*16+c][dt*16+4*quad] = make_ushort4(l0,l1,l2,l3);
#pragma unroll
        for (int reg = 0; reg < 4; ++reg)
            T2[dt * 16 + 4 * quad + reg][st * 16 + c] = bfbits(av[st][reg]);
    }
    __syncthreads();
#pragma unroll
    for (int i = 0; i < 2; ++i) {
        int id = i * 256 + t, row = id >> 3, d8 = (id & 7) * 8;
        size_t qb = ((size_t)(h * S_LEN + s0 + row)) * 64 + d8;
        *(uint4*)&qhi[qb] = *(uint4*)&T0[row][d8];
        *(uint4*)&qlo[qb] = *(uint4*)&T1[row][d8];
        size_t vb = ((size_t)(h * 64 + row)) * S_LEN + s0 + d8;   // row = d, d8 = s-offset
        *(uint4*)&vhi[vb] = *(uint4*)&T2[row][d8];
    }
    // pass B: k hi/lo
    __syncthreads();
#pragma unroll
    for (int st = 0; st < 4; ++st) {
        unsigned short h0,l0,h1,l1,h2,l2,h3,l3;
        splitRN(rk[st][0],h0,l0); splitRN(rk[st][1],h1,l1);
        splitRN(rk[st][2],h2,l2); splitRN(rk[st][3],h3,l3);
        *(ushort4*)&T0[st*16+c][dt*16+4*quad] = make_ushort4(h0,h1,h2,h3);
        *(ushort4*)&T1[st*16+c][dt*16+4*quad] = make_ushort4(l0,l1,l2,l3);
    }
    __syncthreads();
#pragma unroll
    for (int i = 0; i < 2; ++i) {
        int id = i * 256 + t, row = id >> 3, d8 = (id & 7) * 8;
        size_t qb = ((size_t)(h * S_LEN + s0 + row)) * 64 + d8;
        *(uint4*)&khi[qb] = *(uint4*)&T0[row][d8];
        *(uint4*)&klo[qb] = *(uint4*)&T1[row][d8];
    }
}

// MFMA flash attention: double-buffered K/V LDS, 2 barriers/tile.
// XCD-exclusive head swizzle: XCD k owns heads 2k,2k+1 -> KV (1.5 MB) L2-resident.
__global__ __launch_bounds__(256)
void attn_mfma(const unsigned short* __restrict__ qh, const unsigned short* __restrict__ ql,
               const unsigned short* __restrict__ kh, const unsigned short* __restrict__ kl,
               const unsigned short* __restrict__ vh,
               const void* __restrict__ mask, float* __restrict__ out,
               const int* __restrict__ flags) {
    __shared__ unsigned short Kh[2][64][72], Kl[2][64][72];   // [buf][key][d]
    __shared__ unsigned short Vt[2][64][72];                  // [buf][d][key]
    __shared__ unsigned short Sh[64][72], Sl[64][72];         // P: [q-row][key]
    const int menc = flags[0];
    const int t = threadIdx.x;
    // XCD-exclusive head swizzle (bijective: 512 = 8 xcd * 2 * 32 qt)
    const int lin = blockIdx.x + (blockIdx.y << 5);
    const int h = (lin & 7) * 2 + ((lin >> 3) & 1);
    const int s0 = (lin >> 4) * 64;
    const int lane = t & 63, w = t >> 6, quad = lane >> 4, c = lane & 15;

    bf16x8 qfh[2], qfl[2];
#pragma unroll
    for (int ks = 0; ks < 2; ++ks) {
        size_t base = ((size_t)(h * S_LEN + s0 + 16 * w + c)) * 64 + ks * 32 + quad * 8;
        qfh[ks] = *(const bf16x8*)&qh[base];
        qfl[ks] = *(const bf16x8*)&ql[base];
    }
    int mq[4];
#pragma unroll
    for (int i = 0; i < 4; ++i) mq[i] = mask_at(mask, menc, s0 + 16 * w + quad * 4 + i);

    float m_i[4], l_i[4];
#pragma unroll
    for (int i = 0; i < 4; ++i) { m_i[i] = -INFINITY; l_i[i] = 0.0f; }
    f32x4 o_acc[4];
#pragma unroll
    for (int i = 0; i < 4; ++i) o_acc[i] = (f32x4){0.f,0.f,0.f,0.f};

    uint4 pre[6];
#pragma unroll
    for (int i = 0; i < 2; ++i) {
        int id = i * 256 + t, row = id >> 3, col8 = (id & 7) * 8;
        size_t kb = ((size_t)(h * S_LEN + row)) * 64 + col8;
        size_t vb = ((size_t)(h * 64 + row)) * S_LEN + col8;
        pre[0 + i] = *(const uint4*)&kh[kb];
        pre[2 + i] = *(const uint4*)&kl[kb];
        pre[4 + i] = *(const uint4*)&vh[vb];
    }
#pragma unroll
    for (int i = 0; i < 2; ++i) {
        int id = i * 256 + t, row = id >> 3, col8 = (id & 7) * 8;
        *(uint4*)&Kh[0][row][col8] = pre[0 + i];
        *(uint4*)&Kl[0][row][col8] = pre[2 + i];
        *(uint4*)&Vt[0][row][col8] = pre[4 + i];
    }
    __syncthreads();

    int cur = 0;
    for (int kt = 0; kt < 32; ++kt) {
        // issue next-tile global loads first (hidden under QK + softmax)
        if (kt + 1 < 32) {
            const int kb0 = (kt + 1) * 64;
#pragma unroll
            for (int i = 0; i < 2; ++i) {
                int id = i * 256 + t, row = id >> 3, col8 = (id & 7) * 8;
                size_t kb = ((size_t)(h * S_LEN + kb0 + row)) * 64 + col8;
                size_t vb = ((size_t)(h * 64 + row)) * S_LEN + kb0 + col8;
                pre[0 + i] = *(const uint4*)&kh[kb];
                pre[2 + i] = *(const uint4*)&kl[kb];
                pre[4 + i] = *(const uint4*)&vh[vb];
            }
        }
        int mk[4];
#pragma unroll
        for (int nt = 0; nt < 4; ++nt) mk[nt] = mask_at(mask, menc, kt * 64 + 16 * nt + c);

        // ---- QK^T (3-MFMA split) ----
        f32x4 sc[4];
#pragma unroll
        for (int i = 0; i < 4; ++i) sc[i] = (f32x4){0.f,0.f,0.f,0.f};
#pragma unroll
        for (int nt = 0; nt < 4; ++nt)
#pragma unroll
            for (int ks = 0; ks < 2; ++ks) {
                bf16x8 kfh = *(bf16x8*)&Kh[cur][nt * 16 + c][ks * 32 + quad * 8];
                bf16x8 kfl = *(bf16x8*)&Kl[cur][nt * 16 + c][ks * 32 + quad * 8];
                sc[nt] = __builtin_amdgcn_mfma_f32_16x16x32_bf16(qfh[ks], kfh, sc[nt], 0, 0, 0);
                sc[nt] = __builtin_amdgcn_mfma_f32_16x16x32_bf16(qfh[ks], kfl, sc[nt], 0, 0, 0);
                sc[nt] = __builtin_amdgcn_mfma_f32_16x16x32_bf16(qfl[ks], kfh, sc[nt], 0, 0, 0);
            }

        float sm[4][4];
#pragma unroll
        for (int nt = 0; nt < 4; ++nt)
#pragma unroll
            for (int reg = 0; reg < 4; ++reg)
                sm[nt][reg] = (mq[reg] && mk[nt]) ? sc[nt][reg] * 0.125f : -1e30f;

        float rmax[4];
#pragma unroll
        for (int reg = 0; reg < 4; ++reg)
            rmax[reg] = fmaxf(fmaxf(sm[0][reg], sm[1][reg]), fmaxf(sm[2][reg], sm[3][reg]));
#pragma unroll
        for (int off = 1; off <= 8; off <<= 1)
#pragma unroll
            for (int reg = 0; reg < 4; ++reg)
                rmax[reg] = fmaxf(rmax[reg], __shfl_xor(rmax[reg], off, 64));

        float mn[4], alpha[4];
#pragma unroll
        for (int reg = 0; reg < 4; ++reg) {
            mn[reg] = fmaxf(m_i[reg], rmax[reg]);
            alpha[reg] = __expf(m_i[reg] - mn[reg]);
            m_i[reg] = mn[reg];
        }

        float rsum[4] = {0.f, 0.f, 0.f, 0.f};
#pragma unroll
        for (int nt = 0; nt < 4; ++nt)
#pragma unroll
            for (int reg = 0; reg < 4; ++reg) {
                float e = __expf(sm[nt][reg] - mn[reg]);
                rsum[reg] += e;
                unsigned short eh, el;
                splitRN(e, eh, el);
                Sh[16 * w + quad * 4 + reg][16 * nt + c] = eh;
                Sl[16 * w + quad * 4 + reg][16 * nt + c] = el;
            }
#pragma unroll
        for (int off = 1; off <= 8; off <<= 1)
#pragma unroll
            for (int reg = 0; reg < 4; ++reg)
                rsum[reg] += __shfl_xor(rsum[reg], off, 64);
#pragma unroll
        for (int reg = 0; reg < 4; ++reg) l_i[reg] = l_i[reg] * alpha[reg] + rsum[reg];
#pragma unroll
        for (int nt = 0; nt < 4; ++nt)
#pragma unroll
            for (int reg = 0; reg < 4; ++reg) o_acc[nt][reg] *= alpha[reg];

        // stage next tile into the other buffer (pre-loads have had QK+softmax to land)
        if (kt + 1 < 32) {
            const int nxt = cur ^ 1;
#pragma unroll
            for (int i = 0; i < 2; ++i) {
                int id = i * 256 + t, row = id >> 3, col8 = (id & 7) * 8;
                *(uint4*)&Kh[nxt][row][col8] = pre[0 + i];
                *(uint4*)&Kl[nxt][row][col8] = pre[2 + i];
                *(uint4*)&Vt[nxt][row][col8] = pre[4 + i];
            }
        }
        __syncthreads();   // P visible; next K/V visible for next iter

        // ---- PV (2-MFMA, V hi-only) ----
#pragma unroll
        for (int ks = 0; ks < 2; ++ks) {
            bf16x8 pfh = *(bf16x8*)&Sh[16 * w + c][ks * 32 + quad * 8];
            bf16x8 pfl = *(bf16x8*)&Sl[16 * w + c][ks * 32 + quad * 8];
#pragma unroll
            for (int nt = 0; nt < 4; ++nt) {
                bf16x8 vf = *(bf16x8*)&Vt[cur][nt * 16 + c][ks * 32 + quad * 8];
                o_acc[nt] = __builtin_amdgcn_mfma_f32_16x16x32_bf16(pfh, vf, o_acc[nt], 0, 0, 0);
                o_acc[nt] = __builtin_amdgcn_mfma_f32_16x16x32_bf16(pfl, vf, o_acc[nt], 0, 0, 0);
            }
        }
        __syncthreads();   // PV done: S reusable, old buffer free
        cur ^= 1;
    }

#pragma unroll
    for (int reg = 0; reg < 4; ++reg) {
        float inv = 1.0f / l_i[reg];
        int row = s0 + 16 * w + quad * 4 + reg;
#pragma unroll
        for (int nt = 0; nt < 4; ++nt)
            out[(size_t)row * 1024 + h * 64 + nt * 16 + c] = o_acc[nt][reg] * inv;
    }
}

extern "C" void kernel_launch(void* const* d_in, const int* in_sizes, int n_in,
                              void* d_out, int out_size, void* d_ws, size_t ws_size,
                              hipStream_t stream) {
    const float* query = (const float*)d_in[0];
    const float* key   = (const float*)d_in[1];
    const float* value = (const float*)d_in[2];
    const float* b_emb = (const float*)d_in[3];
    const void*  mask  = d_in[4];
    const float* ll    = (const float*)d_in[5];
    const float* bproj = (const float*)d_in[6];
    float* out = (float*)d_out;

    const size_t HSD = (size_t)NHEAD * S_LEN * 64;     // 2M elements
    char* ws = (char*)d_ws;
    int* flags = (int*)ws;
    unsigned short* qhi = (unsigned short*)(ws + 4096);
    unsigned short* qlo = qhi + HSD;
    unsigned short* khi = qlo + HSD;
    unsigned short* klo = khi + HSD;
    unsigned short* vhi = klo + HSD;
    unsigned short* Wh  = vhi + HSD;                   // 4M elements
    unsigned short* Wl  = Wh + 4 * 1048576;            // 4M elements
    // total: 4 KB + 20 MB + 16 MB = ~36 MB

    dim3 pb(256);
    detect_kernel<<<1, 64, 0, stream>>>(mask, flags);
    presplit_w<<<1024, pb, 0, stream>>>(ll, bproj, Wh, Wl);
    proj_fused4<<<dim3(16, 32), pb, 0, stream>>>(query, key, value, b_emb,
                                                 Wh, Wl, qhi, qlo, khi, klo, vhi);
    attn_mfma<<<dim3(32, 16), pb, 0, stream>>>(qhi, qlo, khi, klo, vhi, mask, out, flags);
}